// Round 7
// baseline (154.798 us; speedup 1.0000x reference)
//
#include <hip/hip_runtime.h>
#include <hip/hip_bf16.h>
#include <math.h>

#define Hh 128   // hidden
#define Nn 32    // docs
#define Ll 128   // doc_len
#define W1S 384  // 3H
#define PAD 136  // bf16 elems per LDS row in k_prep (272B stride)
#define SP2 136  // f16 elems per LDS row in k_main (272B stride)

typedef __attribute__((ext_vector_type(8))) short short8;
typedef __attribute__((ext_vector_type(4))) float floatx4;
typedef __attribute__((ext_vector_type(8))) _Float16 f16x8;

__device__ __forceinline__ unsigned short f2bf(float x) {
  __hip_bfloat16 h = __float2bfloat16(x);
  return __builtin_bit_cast(unsigned short, h);
}
__device__ __forceinline__ short8 pack8(float4 a, float4 b) {
  short8 r;
  r[0] = (short)f2bf(a.x); r[1] = (short)f2bf(a.y);
  r[2] = (short)f2bf(a.z); r[3] = (short)f2bf(a.w);
  r[4] = (short)f2bf(b.x); r[5] = (short)f2bf(b.y);
  r[6] = (short)f2bf(b.z); r[7] = (short)f2bf(b.w);
  return r;
}
__device__ __forceinline__ f16x8 cvt8h(float4 a, float4 b) {
  f16x8 r;
  r[0] = (_Float16)a.x; r[1] = (_Float16)a.y;
  r[2] = (_Float16)a.z; r[3] = (_Float16)a.w;
  r[4] = (_Float16)b.x; r[5] = (_Float16)b.y;
  r[6] = (_Float16)b.z; r[7] = (_Float16)b.w;
  return r;
}

// Grid 128: block b -> n = b>>2, which = (b>>1)&1 (0:Bt 1:CtT), mh = b&1 (M-half).
// Bt row-major [k][g] with b1 folded; Ct TRANSPOSED: CtT[g][k] (float4 epilogue
// loads in k_main). scale folded at staging.
__launch_bounds__(256, 2)
__global__ void k_prep(const float* __restrict__ wei, const int* __restrict__ wmask,
                       const float* __restrict__ doc, const float* __restrict__ q,
                       const float* __restrict__ W1, const float* __restrict__ b1,
                       float* __restrict__ Bt, float* __restrict__ Ct) {
  __shared__ __align__(16) short Wsb[Hh * PAD];   // bf16(W1b or W1c)
  __shared__ __align__(16) short docb[64 * PAD];  // bf16(doc * scale), this block's 64 rows
  __shared__ __align__(16) float red[2][Hh];
  __shared__ __align__(16) float scale[Hh];

  int b = blockIdx.x;
  int n = b >> 2, which = (b >> 1) & 1, mh = b & 1;
  int tid = threadIdx.x;
  const float* docn = doc + (size_t)n * Ll * Hh;
  int e8 = (tid & 15) * 8;

  float4 dreg[4][2];
#pragma unroll
  for (int p = 0; p < 4; ++p) {
    int row = mh * 64 + p * 16 + (tid >> 4);
    const float4* dp = (const float4*)(docn + (size_t)row * Hh + e8);
    dreg[p][0] = dp[0]; dreg[p][1] = dp[1];
  }
#pragma unroll
  for (int p = 0; p < 8; ++p) {
    int row = p * 16 + (tid >> 4);
    const float4* wp = (const float4*)(W1 + (size_t)row * W1S + (which + 1) * Hh + e8);
    *(short8*)(Wsb + row * PAD + e8) = pack8(wp[0], wp[1]);
  }
  if (which == 1) {
    if (tid < Hh) scale[tid] = q[(n >> 3) * Hh + tid];
  } else {
    int e = tid & 127, halfl = tid >> 7;
    const float* wp = wei + (size_t)n * Ll * Hh + (size_t)halfl * 64 * Hh + e;
    const int* mp = wmask + n * Ll + halfl * 64;
    float a = 0.f;
#pragma unroll 16
    for (int l = 0; l < 64; ++l) a = fmaf((float)mp[l], wp[(size_t)l * Hh], a);
    red[halfl][e] = a;
  }
  __syncthreads();
  if (which == 0 && tid < Hh) scale[tid] = red[0][tid] + red[1][tid];
  __syncthreads();
  {
    float s[8];
#pragma unroll
    for (int i = 0; i < 8; ++i) s[i] = scale[e8 + i];
#pragma unroll
    for (int p = 0; p < 4; ++p) {
      int r = p * 16 + (tid >> 4);
      float4 a = dreg[p][0], bq = dreg[p][1];
      a.x *= s[0]; a.y *= s[1]; a.z *= s[2]; a.w *= s[3];
      bq.x *= s[4]; bq.y *= s[5]; bq.z *= s[6]; bq.w *= s[7];
      *(short8*)(docb + r * PAD + e8) = pack8(a, bq);
    }
  }
  __syncthreads();

  int lane = tid & 63, w = tid >> 6;
  int l15 = lane & 15, quad = lane >> 4;
  floatx4 acc[8];
#pragma unroll
  for (int nt = 0; nt < 8; ++nt) acc[nt] = (floatx4){0.f, 0.f, 0.f, 0.f};
#pragma unroll
  for (int c = 0; c < 4; ++c) {
    int eo = c * 32 + quad * 8;
    short8 af = *(const short8*)(docb + (w * 16 + l15) * PAD + eo);
    short8 bfr[8];
#pragma unroll
    for (int nt = 0; nt < 8; ++nt)
      bfr[nt] = *(const short8*)(Wsb + (nt * 16 + l15) * PAD + eo);
#pragma unroll
    for (int nt = 0; nt < 8; ++nt)
      acc[nt] = __builtin_amdgcn_mfma_f32_16x16x32_bf16(af, bfr[nt], acc[nt], 0, 0, 0);
  }

  if (which) {
    // CtT[g][k] float4 stores: g = nt*16+l15, k = mh*64 + w*16 + quad*4 + r
    float* outp = Ct + (size_t)n * Ll * Hh;
#pragma unroll
    for (int nt = 0; nt < 8; ++nt) {
      float4 v;
      v.x = acc[nt][0]; v.y = acc[nt][1]; v.z = acc[nt][2]; v.w = acc[nt][3];
      *(float4*)(outp + (size_t)(nt * 16 + l15) * Hh + (mh * 64 + w * 16 + quad * 4)) = v;
    }
  } else {
    float* outp = Bt + (size_t)n * Ll * Hh;
#pragma unroll
    for (int nt = 0; nt < 8; ++nt) {
      int g = nt * 16 + l15;
      float badd = b1[g];
#pragma unroll
      for (int r = 0; r < 4; ++r) {
        int k = mh * 64 + w * 16 + quad * 4 + r;
        outp[(size_t)k * Hh + g] = acc[nt][r] + badd;
      }
    }
  }
}

// v7: one block per (n,j), critical-path-compressed:
// 3 barriers (was 5); one-shot fp16 staging of full doc + W1a (70.7 KB);
// epilogue reads CtT as 8 float4 (nt-outer, 4 accumulators -> spill-lean);
// Bt/w2 hoisted above the stage barrier; AV reads doc fp16 from LDS
// (no global loads in the tail) by waves 0-1, no LDS reduction round trip.
__launch_bounds__(512, 4)
__global__ void k_main(const float* __restrict__ doc, const int* __restrict__ dmask,
                       const float* __restrict__ W1,
                       const float* __restrict__ w2, const float* __restrict__ b2,
                       const float* __restrict__ Bt, const float* __restrict__ Ct,
                       float* __restrict__ out) {
  __shared__ __align__(16) _Float16 As[Hh * SP2];  // fp16(W1a)
  __shared__ __align__(16) _Float16 Bs[Hh * SP2];  // fp16(doc)
  __shared__ __align__(16) float sc[Ll];
  __shared__ __align__(16) float scw[Ll];

  int bid = blockIdx.x;
  int n = bid & 31, j = bid >> 5;   // XCD-locality swizzle
  int tid = threadIdx.x;
  const float* docn = doc + (size_t)n * Ll * Hh;
  size_t orow = ((size_t)n * Ll + j) * Hh;

  if (dmask[n * Ll + j] == 0) {     // fully-masked row -> exact zeros (~50% of blocks)
    if (tid < Hh) out[orow + tid] = 0.f;
    return;
  }

  int lane = tid & 63, wv = tid >> 6;   // 8 waves x 16 k-rows
  int l15 = lane & 15, quad = lane >> 4;

  // hoist epilogue row-operands: their L2 latency hides under staging
  const float c2 = 2.885390081777927f;  // 2*log2(e)
  float bbc[8], w2r[8];
  {
    const float* btrow = Bt + orow;
#pragma unroll
    for (int nt = 0; nt < 8; ++nt) {
      int g = nt * 16 + l15;
      bbc[nt] = btrow[g] * c2;           // b1 folded into Bt by k_prep
      w2r[nt] = w2[g];
    }
  }

  // one-shot staging: thread (row = tid>>2, 32-elem segment = (tid&3)*32)
  {
    int row = tid >> 2, seg = (tid & 3) * 32;
    const float4* dsrc = (const float4*)(docn + (size_t)row * Hh + seg);
    const float4* wsrc = (const float4*)(W1 + (size_t)row * W1S + seg);
#pragma unroll
    for (int i = 0; i < 4; ++i) {
      *(f16x8*)(Bs + row * SP2 + seg + i * 8) = cvt8h(dsrc[2 * i], dsrc[2 * i + 1]);
      *(f16x8*)(As + row * SP2 + seg + i * 8) = cvt8h(wsrc[2 * i], wsrc[2 * i + 1]);
    }
  }
  __syncthreads();  // barrier 1

  floatx4 acc[8];
#pragma unroll
  for (int nt = 0; nt < 8; ++nt) acc[nt] = (floatx4){0.f, 0.f, 0.f, 0.f};
#pragma unroll
  for (int c = 0; c < 4; ++c) {
    int eo = c * 32 + quad * 8;
    f16x8 dr = *(const f16x8*)(Bs + (wv * 16 + l15) * SP2 + eo);
    f16x8 jr = *(const f16x8*)(Bs + j * SP2 + eo);   // uniform row -> broadcast
    f16x8 af = dr * jr;                               // 4x v_pk_mul_f16
#pragma unroll
    for (int nt = 0; nt < 8; ++nt) {
      f16x8 bfr = *(const f16x8*)(As + (nt * 16 + l15) * SP2 + eo);
      acc[nt] = __builtin_amdgcn_mfma_f32_16x16x32_f16(af, bfr, acc[nt], 0, 0, 0);
    }
  }

  // epilogue: nt-outer, one float4 CtT load per nt, 4 running dot-partials
  {
    const float* ctn = Ct + (size_t)n * Ll * Hh;     // CtT[g][k]
    float p0 = 0.f, p1 = 0.f, p2 = 0.f, p3 = 0.f;
    int kbase = wv * 16 + quad * 4;
#pragma unroll
    for (int nt = 0; nt < 8; ++nt) {
      float4 ct4 = *(const float4*)(ctn + (size_t)(nt * 16 + l15) * Hh + kbase);
      float bb = bbc[nt], wr = w2r[nt];
      {
        float a2 = fmaf(acc[nt][0] + ct4.x, c2, bb);
        float e = exp2f(a2);
        p0 = fmaf(fmaf(-2.f, __builtin_amdgcn_rcpf(e + 1.f), 1.f), wr, p0);
      }
      {
        float a2 = fmaf(acc[nt][1] + ct4.y, c2, bb);
        float e = exp2f(a2);
        p1 = fmaf(fmaf(-2.f, __builtin_amdgcn_rcpf(e + 1.f), 1.f), wr, p1);
      }
      {
        float a2 = fmaf(acc[nt][2] + ct4.z, c2, bb);
        float e = exp2f(a2);
        p2 = fmaf(fmaf(-2.f, __builtin_amdgcn_rcpf(e + 1.f), 1.f), wr, p2);
      }
      {
        float a2 = fmaf(acc[nt][3] + ct4.w, c2, bb);
        float e = exp2f(a2);
        p3 = fmaf(fmaf(-2.f, __builtin_amdgcn_rcpf(e + 1.f), 1.f), wr, p3);
      }
    }
#pragma unroll
    for (int off = 1; off <= 8; off <<= 1) {
      p0 += __shfl_xor(p0, off);
      p1 += __shfl_xor(p1, off);
      p2 += __shfl_xor(p2, off);
      p3 += __shfl_xor(p3, off);
    }
    if (l15 == 0) {
      sc[kbase + 0] = p0; sc[kbase + 1] = p1;
      sc[kbase + 2] = p2; sc[kbase + 3] = p3;
    }
  }
  __syncthreads();  // barrier 2

  // redundant per-wave masked softmax (identical values from all 8 waves)
  {
    float b2v = b2[0];
    const float inv = 0.088388347648318447f;  // 1/sqrt(128)
    const int* dmn = dmask + n * Ll;
    int m0 = dmn[lane], m1 = dmn[lane + 64];
    float s0 = (sc[lane] + b2v) * inv;
    float s1 = (sc[lane + 64] + b2v) * inv;
    s0 = m0 ? s0 : -1e9f;
    s1 = m1 ? s1 : -1e9f;
    float mx = fmaxf(s0, s1);
#pragma unroll
    for (int off = 32; off; off >>= 1) mx = fmaxf(mx, __shfl_xor(mx, off));
    float ex0 = __expf(s0 - mx), ex1 = __expf(s1 - mx);
    float sm = ex0 + ex1;
#pragma unroll
    for (int off = 32; off; off >>= 1) sm += __shfl_xor(sm, off);
    float rden = 1.f / sm;
    scw[lane] = m0 ? ex0 * rden : 0.f;
    scw[lane + 64] = m1 ? ex1 * rden : 0.f;
  }
  __syncthreads();  // barrier 3 (last; waves 2-7 fall through to exit)

  // AV from LDS fp16 doc: out[j,h] = sum_k scw[k] * doc[n,k,h]; waves 0-1 only
  if (tid < Ll) {
    int h = tid;
    float o0 = 0.f, o1 = 0.f, o2 = 0.f, o3 = 0.f;
#pragma unroll 8
    for (int kk = 0; kk < Ll; kk += 4) {
      o0 = fmaf(scw[kk + 0], (float)Bs[(kk + 0) * SP2 + h], o0);
      o1 = fmaf(scw[kk + 1], (float)Bs[(kk + 1) * SP2 + h], o1);
      o2 = fmaf(scw[kk + 2], (float)Bs[(kk + 2) * SP2 + h], o2);
      o3 = fmaf(scw[kk + 3], (float)Bs[(kk + 3) * SP2 + h], o3);
    }
    out[orow + h] = (o0 + o1) + (o2 + o3);
  }
}

extern "C" void kernel_launch(void* const* d_in, const int* in_sizes, int n_in,
                              void* d_out, int out_size, void* d_ws, size_t ws_size,
                              hipStream_t stream) {
  const float* wei   = (const float*)d_in[0];
  const int*   wmask = (const int*)d_in[1];
  const float* doc   = (const float*)d_in[2];
  const int*   dmask = (const int*)d_in[3];
  const float* q     = (const float*)d_in[4];
  const float* W1    = (const float*)d_in[5];
  const float* b1    = (const float*)d_in[6];
  const float* w2    = (const float*)d_in[7];
  const float* b2    = (const float*)d_in[8];
  float* out = (float*)d_out;

  float* ws = (float*)d_ws;
  float* Bt = ws;                           // N*L*H [k][g], b1 folded in
  float* Ct = Bt + (size_t)Nn * Ll * Hh;    // N*L*H TRANSPOSED: CtT[g][k]

  k_prep<<<Nn * 4, 256, 0, stream>>>(wei, wmask, doc, q, W1, b1, Bt, Ct);
  k_main<<<Nn * Ll, 512, 0, stream>>>(doc, dmask, W1, w2, b2, Bt, Ct, out);
}

// Round 8
// 147.862 us; speedup vs baseline: 1.0469x; 1.0469x over previous
//
#include <hip/hip_runtime.h>
#include <hip/hip_bf16.h>
#include <math.h>

#define Hh 128   // hidden
#define Nn 32    // docs
#define Ll 128   // doc_len
#define W1S 384  // 3H
#define PAD 136  // bf16 elems per LDS row in k_prep (272B stride)
#define EP 64    // e-elems per K-pass in k_main
#define SP 72    // f16 elems per LDS row in k_main (144B stride)

typedef __attribute__((ext_vector_type(8))) short short8;
typedef __attribute__((ext_vector_type(4))) float floatx4;
typedef __attribute__((ext_vector_type(8))) _Float16 f16x8;

__device__ __forceinline__ unsigned short f2bf(float x) {
  __hip_bfloat16 h = __float2bfloat16(x);
  return __builtin_bit_cast(unsigned short, h);
}
__device__ __forceinline__ short8 pack8(float4 a, float4 b) {
  short8 r;
  r[0] = (short)f2bf(a.x); r[1] = (short)f2bf(a.y);
  r[2] = (short)f2bf(a.z); r[3] = (short)f2bf(a.w);
  r[4] = (short)f2bf(b.x); r[5] = (short)f2bf(b.y);
  r[6] = (short)f2bf(b.z); r[7] = (short)f2bf(b.w);
  return r;
}
__device__ __forceinline__ f16x8 cvt8h(float4 a, float4 b) {
  f16x8 r;
  r[0] = (_Float16)a.x; r[1] = (_Float16)a.y;
  r[2] = (_Float16)a.z; r[3] = (_Float16)a.w;
  r[4] = (_Float16)b.x; r[5] = (_Float16)b.y;
  r[6] = (_Float16)b.z; r[7] = (_Float16)b.w;
  return r;
}

// v8 k_prep: Bt only (Ct is now fused into k_main's GEMM). Grid 64:
// block b -> n = b>>1, mh = b&1 (M-half). scale (= mask^T wei) folded at
// staging; b1 folded into Bt.
__launch_bounds__(256, 2)
__global__ void k_prep(const float* __restrict__ wei, const int* __restrict__ wmask,
                       const float* __restrict__ doc,
                       const float* __restrict__ W1, const float* __restrict__ b1,
                       float* __restrict__ Bt) {
  __shared__ __align__(16) short Wsb[Hh * PAD];   // bf16(W1b)
  __shared__ __align__(16) short docb[64 * PAD];  // bf16(doc * scale), this block's 64 rows
  __shared__ __align__(16) float red[2][Hh];
  __shared__ __align__(16) float scale[Hh];

  int b = blockIdx.x;
  int n = b >> 1, mh = b & 1;
  int tid = threadIdx.x;
  const float* docn = doc + (size_t)n * Ll * Hh;
  int e8 = (tid & 15) * 8;

  float4 dreg[4][2];
#pragma unroll
  for (int p = 0; p < 4; ++p) {
    int row = mh * 64 + p * 16 + (tid >> 4);
    const float4* dp = (const float4*)(docn + (size_t)row * Hh + e8);
    dreg[p][0] = dp[0]; dreg[p][1] = dp[1];
  }
#pragma unroll
  for (int p = 0; p < 8; ++p) {
    int row = p * 16 + (tid >> 4);
    const float4* wp = (const float4*)(W1 + (size_t)row * W1S + Hh + e8);  // W1b
    *(short8*)(Wsb + row * PAD + e8) = pack8(wp[0], wp[1]);
  }
  {
    int e = tid & 127, halfl = tid >> 7;
    const float* wp = wei + (size_t)n * Ll * Hh + (size_t)halfl * 64 * Hh + e;
    const int* mp = wmask + n * Ll + halfl * 64;
    float a = 0.f;
#pragma unroll 16
    for (int l = 0; l < 64; ++l) a = fmaf((float)mp[l], wp[(size_t)l * Hh], a);
    red[halfl][e] = a;
  }
  __syncthreads();
  if (tid < Hh) scale[tid] = red[0][tid] + red[1][tid];
  __syncthreads();
  {
    float s[8];
#pragma unroll
    for (int i = 0; i < 8; ++i) s[i] = scale[e8 + i];
#pragma unroll
    for (int p = 0; p < 4; ++p) {
      int r = p * 16 + (tid >> 4);
      float4 a = dreg[p][0], bq = dreg[p][1];
      a.x *= s[0]; a.y *= s[1]; a.z *= s[2]; a.w *= s[3];
      bq.x *= s[4]; bq.y *= s[5]; bq.z *= s[6]; bq.w *= s[7];
      *(short8*)(docb + r * PAD + e8) = pack8(a, bq);
    }
  }
  __syncthreads();

  int lane = tid & 63, w = tid >> 6;
  int l15 = lane & 15, quad = lane >> 4;
  floatx4 acc[8];
#pragma unroll
  for (int nt = 0; nt < 8; ++nt) acc[nt] = (floatx4){0.f, 0.f, 0.f, 0.f};
#pragma unroll
  for (int c = 0; c < 4; ++c) {
    int eo = c * 32 + quad * 8;
    short8 af = *(const short8*)(docb + (w * 16 + l15) * PAD + eo);
    short8 bfr[8];
#pragma unroll
    for (int nt = 0; nt < 8; ++nt)
      bfr[nt] = *(const short8*)(Wsb + (nt * 16 + l15) * PAD + eo);
#pragma unroll
    for (int nt = 0; nt < 8; ++nt)
      acc[nt] = __builtin_amdgcn_mfma_f32_16x16x32_bf16(af, bfr[nt], acc[nt], 0, 0, 0);
  }

  float* outp = Bt + (size_t)n * Ll * Hh;
#pragma unroll
  for (int nt = 0; nt < 8; ++nt) {
    int g = nt * 16 + l15;
    float badd = b1[g];
#pragma unroll
    for (int r = 0; r < 4; ++r) {
      int k = mh * 64 + w * 16 + quad * 4 + r;
      outp[(size_t)k * Hh + g] = acc[nt][r] + badd;
    }
  }
}

// v8 k_main: R6 skeleton + Ct FUSED into the GEMM. Per K-window c:
// af = dr*jr feeds W1a fragments, ag = dr*q8 feeds W1c fragments, both into
// the same acc -> the epilogue's 32 scattered Ct L2 loads per thread and the
// 2MB Ct round trip vanish. 3 staged windows (doc/W1a/W1c), LDS ~56.3 KB.
__launch_bounds__(512, 4)
__global__ void k_main(const float* __restrict__ doc, const int* __restrict__ dmask,
                       const float* __restrict__ W1, const float* __restrict__ q,
                       const float* __restrict__ w2, const float* __restrict__ b2,
                       const float* __restrict__ Bt, float* __restrict__ out) {
  __shared__ __align__(16) _Float16 Aw[Hh * SP];  // fp16(W1a), e-window
  __shared__ __align__(16) _Float16 Cw[Hh * SP];  // fp16(W1c), e-window
  __shared__ __align__(16) _Float16 Dw[Hh * SP];  // fp16(doc), e-window
  __shared__ __align__(16) float sc[Ll];
  __shared__ __align__(16) float scw[Ll];

  int bid = blockIdx.x;
  int n = bid & 31, j = bid >> 5;   // XCD-locality swizzle
  int tid = threadIdx.x;
  const float* docn = doc + (size_t)n * Ll * Hh;
  size_t orow = ((size_t)n * Ll + j) * Hh;

  if (dmask[n * Ll + j] == 0) {     // fully-masked row -> exact zeros (~50% of blocks)
    if (tid < Hh) out[orow + tid] = 0.f;
    return;
  }

  int lane = tid & 63, wv = tid >> 6;   // 8 waves x 16 k-rows
  int l15 = lane & 15, quad = lane >> 4;
  int grow = tid >> 2, seg = (tid & 3) * 16;  // staging: row 0..127, 16-e segment

  // q fragments (block-uniform row, lane-dependent quad window): 4 x f16x8
  f16x8 q8[4];
  {
    const float* qn = q + (size_t)(n >> 3) * Hh;
#pragma unroll
    for (int pc = 0; pc < 4; ++pc) {
      const float4* qp = (const float4*)(qn + pc * 32 + quad * 8);
      q8[pc] = cvt8h(qp[0], qp[1]);
    }
  }

  floatx4 acc[8];
#pragma unroll
  for (int nt = 0; nt < 8; ++nt) acc[nt] = (floatx4){0.f, 0.f, 0.f, 0.f};

#pragma unroll
  for (int p = 0; p < 2; ++p) {
    if (p) __syncthreads();  // all waves done reading pass-0 windows
    // stage this pass's 64-e windows of doc, W1a, W1c as fp16
    {
      const float4* dsrc = (const float4*)(docn + (size_t)grow * Hh + p * EP + seg);
      const float4* wa = (const float4*)(W1 + (size_t)grow * W1S + p * EP + seg);
      const float4* wc = (const float4*)(W1 + (size_t)grow * W1S + 2 * Hh + p * EP + seg);
      float4 d0 = dsrc[0], d1 = dsrc[1], d2 = dsrc[2], d3 = dsrc[3];
      float4 a0 = wa[0], a1 = wa[1], a2 = wa[2], a3 = wa[3];
      float4 c0 = wc[0], c1 = wc[1], c2v = wc[2], c3 = wc[3];
      *(f16x8*)(Dw + grow * SP + seg) = cvt8h(d0, d1);
      *(f16x8*)(Dw + grow * SP + seg + 8) = cvt8h(d2, d3);
      *(f16x8*)(Aw + grow * SP + seg) = cvt8h(a0, a1);
      *(f16x8*)(Aw + grow * SP + seg + 8) = cvt8h(a2, a3);
      *(f16x8*)(Cw + grow * SP + seg) = cvt8h(c0, c1);
      *(f16x8*)(Cw + grow * SP + seg + 8) = cvt8h(c2v, c3);
    }
    __syncthreads();
    // GEMM over this 64-e window: A-part (d_k*d_j @ W1a) + C-part (d_k*q @ W1c)
#pragma unroll
    for (int c = 0; c < 2; ++c) {
      int eo = c * 32 + quad * 8;
      f16x8 dr = *(const f16x8*)(Dw + (wv * 16 + l15) * SP + eo);
      f16x8 jr = *(const f16x8*)(Dw + j * SP + eo);   // uniform row -> broadcast
      f16x8 af = dr * jr;                              // 4x v_pk_mul_f16
      f16x8 ag = dr * q8[p * 2 + c];                   // 4x v_pk_mul_f16
#pragma unroll
      for (int nt = 0; nt < 8; ++nt) {
        f16x8 ba = *(const f16x8*)(Aw + (nt * 16 + l15) * SP + eo);
        acc[nt] = __builtin_amdgcn_mfma_f32_16x16x32_f16(af, ba, acc[nt], 0, 0, 0);
      }
#pragma unroll
      for (int nt = 0; nt < 8; ++nt) {
        f16x8 bc = *(const f16x8*)(Cw + (nt * 16 + l15) * SP + eo);
        acc[nt] = __builtin_amdgcn_mfma_f32_16x16x32_f16(ag, bc, acc[nt], 0, 0, 0);
      }
    }
  }

  // epilogue: tanh(acc + Bt[j,g]) . w2 -> sc[k]   (b1 in Bt; Ct already in acc)
  const float c2 = 2.885390081777927f;  // 2*log2(e)
  float bbc[8], w2r[8];
  const float* btrow = Bt + orow;
#pragma unroll
  for (int nt = 0; nt < 8; ++nt) {
    int g = nt * 16 + l15;
    bbc[nt] = btrow[g] * c2;
    w2r[nt] = w2[g];
  }
#pragma unroll
  for (int r = 0; r < 4; ++r) {
    int k = wv * 16 + quad * 4 + r;
    float p = 0.f;
#pragma unroll
    for (int nt = 0; nt < 8; ++nt) {
      float a2 = fmaf(acc[nt][r], c2, bbc[nt]);
      float e = exp2f(a2);
      float th = fmaf(-2.f, __builtin_amdgcn_rcpf(e + 1.f), 1.f);
      p = fmaf(th, w2r[nt], p);
    }
    p += __shfl_xor(p, 1);
    p += __shfl_xor(p, 2);
    p += __shfl_xor(p, 4);
    p += __shfl_xor(p, 8);
    if (l15 == 0) sc[k] = p;
  }
  __syncthreads();

  // redundant per-wave masked softmax (no extra barriers)
  {
    float b2v = b2[0];
    const float inv = 0.088388347648318447f;  // 1/sqrt(128)
    const int* dmn = dmask + n * Ll;
    int m0 = dmn[lane], m1 = dmn[lane + 64];
    float s0 = (sc[lane] + b2v) * inv;
    float s1 = (sc[lane + 64] + b2v) * inv;
    s0 = m0 ? s0 : -1e9f;
    s1 = m1 ? s1 : -1e9f;
    float mx = fmaxf(s0, s1);
#pragma unroll
    for (int off = 32; off; off >>= 1) mx = fmaxf(mx, __shfl_xor(mx, off));
    float ex0 = __expf(s0 - mx), ex1 = __expf(s1 - mx);
    float sm = ex0 + ex1;
#pragma unroll
    for (int off = 32; off; off >>= 1) sm += __shfl_xor(sm, off);
    float rden = 1.f / sm;
    scw[lane] = m0 ? ex0 * rden : 0.f;       // all 8 waves write identical values
    scw[lane + 64] = m1 ? ex1 * rden : 0.f;
  }
  __syncthreads();

  // out[j,h] = sum_k w[k] * doc[n,k,h] ; 4-way k-split across the 512 threads
  float* ored = (float*)Aw;  // Aw dead after GEMM (all waves past last barrier)
  int qk = tid >> 7, h = tid & 127;
  const float* dbase = docn + (size_t)qk * 32 * Hh + h;
  float o = 0.f;
#pragma unroll 8
  for (int kk = 0; kk < 32; ++kk)
    o = fmaf(scw[qk * 32 + kk], dbase[(size_t)kk * Hh], o);
  ored[qk * Hh + h] = o;
  __syncthreads();
  if (tid < Ll)
    out[orow + tid] = ored[tid] + ored[Hh + tid] + ored[2 * Hh + tid] + ored[3 * Hh + tid];
}

extern "C" void kernel_launch(void* const* d_in, const int* in_sizes, int n_in,
                              void* d_out, int out_size, void* d_ws, size_t ws_size,
                              hipStream_t stream) {
  const float* wei   = (const float*)d_in[0];
  const int*   wmask = (const int*)d_in[1];
  const float* doc   = (const float*)d_in[2];
  const int*   dmask = (const int*)d_in[3];
  const float* q     = (const float*)d_in[4];
  const float* W1    = (const float*)d_in[5];
  const float* b1    = (const float*)d_in[6];
  const float* w2    = (const float*)d_in[7];
  const float* b2    = (const float*)d_in[8];
  float* out = (float*)d_out;

  float* Bt = (float*)d_ws;                 // N*L*H (b1 folded in); Ct no longer exists

  k_prep<<<Nn * 2, 256, 0, stream>>>(wei, wmask, doc, W1, b1, Bt);
  k_main<<<Nn * Ll, 512, 0, stream>>>(doc, dmask, W1, q, w2, b2, Bt, out);
}

// Round 9
// 124.282 us; speedup vs baseline: 1.2455x; 1.1897x over previous
//
#include <hip/hip_runtime.h>
#include <hip/hip_bf16.h>
#include <math.h>

#define Hh 128   // hidden
#define Nn 32    // docs
#define Ll 128   // doc_len
#define W1S 384  // 3H
#define PAD 136  // bf16 elems per LDS row in k_prep (272B stride)
#define EP 64    // e-elems per K-pass in k_main
#define SP 72    // f16 elems per LDS row in k_main (144B stride)

typedef __attribute__((ext_vector_type(8))) short short8;
typedef __attribute__((ext_vector_type(4))) float floatx4;
typedef __attribute__((ext_vector_type(8))) _Float16 f16x8;

__device__ __forceinline__ unsigned short f2bf(float x) {
  __hip_bfloat16 h = __float2bfloat16(x);
  return __builtin_bit_cast(unsigned short, h);
}
__device__ __forceinline__ short8 pack8(float4 a, float4 b) {
  short8 r;
  r[0] = (short)f2bf(a.x); r[1] = (short)f2bf(a.y);
  r[2] = (short)f2bf(a.z); r[3] = (short)f2bf(a.w);
  r[4] = (short)f2bf(b.x); r[5] = (short)f2bf(b.y);
  r[6] = (short)f2bf(b.z); r[7] = (short)f2bf(b.w);
  return r;
}
__device__ __forceinline__ f16x8 cvt8h(float4 a, float4 b) {
  f16x8 r;
  r[0] = (_Float16)a.x; r[1] = (_Float16)a.y;
  r[2] = (_Float16)a.z; r[3] = (_Float16)a.w;
  r[4] = (_Float16)b.x; r[5] = (_Float16)b.y;
  r[6] = (_Float16)b.z; r[7] = (_Float16)b.w;
  return r;
}

// Grid 128: block b -> n = b>>2, which = (b>>1)&1 (0:Bt 1:Ct), mh = b&1.
// v9: which==0 blocks ALSO write doc_h (fp16 raw doc, j-invariant — so k_main
// stages doc with zero converts); Ct stored fp16 (ws budget). Bt fp32, b1 folded.
__launch_bounds__(256, 2)
__global__ void k_prep(const float* __restrict__ wei, const int* __restrict__ wmask,
                       const float* __restrict__ doc, const float* __restrict__ q,
                       const float* __restrict__ W1, const float* __restrict__ b1,
                       float* __restrict__ Bt, _Float16* __restrict__ Ct16,
                       _Float16* __restrict__ doc_h) {
  __shared__ __align__(16) short Wsb[Hh * PAD];   // bf16(W1b or W1c)
  __shared__ __align__(16) short docb[64 * PAD];  // bf16(doc * scale), this block's 64 rows
  __shared__ __align__(16) float red[2][Hh];
  __shared__ __align__(16) float scale[Hh];

  int b = blockIdx.x;
  int n = b >> 2, which = (b >> 1) & 1, mh = b & 1;
  int tid = threadIdx.x;
  const float* docn = doc + (size_t)n * Ll * Hh;
  int e8 = (tid & 15) * 8;

  float4 dreg[4][2];
#pragma unroll
  for (int p = 0; p < 4; ++p) {
    int row = mh * 64 + p * 16 + (tid >> 4);
    const float4* dp = (const float4*)(docn + (size_t)row * Hh + e8);
    dreg[p][0] = dp[0]; dreg[p][1] = dp[1];
  }
  // j-invariant fp16 doc for k_main staging (which==0 blocks cover all rows)
  if (which == 0) {
    _Float16* dh = doc_h + (size_t)n * Ll * Hh;
#pragma unroll
    for (int p = 0; p < 4; ++p) {
      int row = mh * 64 + p * 16 + (tid >> 4);
      *(f16x8*)(dh + (size_t)row * Hh + e8) = cvt8h(dreg[p][0], dreg[p][1]);
    }
  }
#pragma unroll
  for (int p = 0; p < 8; ++p) {
    int row = p * 16 + (tid >> 4);
    const float4* wp = (const float4*)(W1 + (size_t)row * W1S + (which + 1) * Hh + e8);
    *(short8*)(Wsb + row * PAD + e8) = pack8(wp[0], wp[1]);
  }
  if (which == 1) {
    if (tid < Hh) scale[tid] = q[(n >> 3) * Hh + tid];
  } else {
    int e = tid & 127, halfl = tid >> 7;
    const float* wp = wei + (size_t)n * Ll * Hh + (size_t)halfl * 64 * Hh + e;
    const int* mp = wmask + n * Ll + halfl * 64;
    float a = 0.f;
#pragma unroll 16
    for (int l = 0; l < 64; ++l) a = fmaf((float)mp[l], wp[(size_t)l * Hh], a);
    red[halfl][e] = a;
  }
  __syncthreads();
  if (which == 0 && tid < Hh) scale[tid] = red[0][tid] + red[1][tid];
  __syncthreads();
  {
    float s[8];
#pragma unroll
    for (int i = 0; i < 8; ++i) s[i] = scale[e8 + i];
#pragma unroll
    for (int p = 0; p < 4; ++p) {
      int r = p * 16 + (tid >> 4);
      float4 a = dreg[p][0], bq = dreg[p][1];
      a.x *= s[0]; a.y *= s[1]; a.z *= s[2]; a.w *= s[3];
      bq.x *= s[4]; bq.y *= s[5]; bq.z *= s[6]; bq.w *= s[7];
      *(short8*)(docb + r * PAD + e8) = pack8(a, bq);
    }
  }
  __syncthreads();

  int lane = tid & 63, w = tid >> 6;
  int l15 = lane & 15, quad = lane >> 4;
  floatx4 acc[8];
#pragma unroll
  for (int nt = 0; nt < 8; ++nt) acc[nt] = (floatx4){0.f, 0.f, 0.f, 0.f};
#pragma unroll
  for (int c = 0; c < 4; ++c) {
    int eo = c * 32 + quad * 8;
    short8 af = *(const short8*)(docb + (w * 16 + l15) * PAD + eo);
    short8 bfr[8];
#pragma unroll
    for (int nt = 0; nt < 8; ++nt)
      bfr[nt] = *(const short8*)(Wsb + (nt * 16 + l15) * PAD + eo);
#pragma unroll
    for (int nt = 0; nt < 8; ++nt)
      acc[nt] = __builtin_amdgcn_mfma_f32_16x16x32_bf16(af, bfr[nt], acc[nt], 0, 0, 0);
  }

  if (which) {
    _Float16* outp = Ct16 + (size_t)n * Ll * Hh;
#pragma unroll
    for (int nt = 0; nt < 8; ++nt) {
      int g = nt * 16 + l15;
#pragma unroll
      for (int r = 0; r < 4; ++r) {
        int k = mh * 64 + w * 16 + quad * 4 + r;
        outp[(size_t)k * Hh + g] = (_Float16)acc[nt][r];
      }
    }
  } else {
    float* outp = Bt + (size_t)n * Ll * Hh;
#pragma unroll
    for (int nt = 0; nt < 8; ++nt) {
      int g = nt * 16 + l15;
      float badd = b1[g];
#pragma unroll
      for (int r = 0; r < 4; ++r) {
        int k = mh * 64 + w * 16 + quad * 4 + r;
        outp[(size_t)k * Hh + g] = acc[nt][r] + badd;
      }
    }
  }
}

// v9 k_main = R6 verbatim EXCEPT: doc staged from pre-converted doc_h
// (2x f16x8 load + 2 LDS stores per thread per pass, ZERO cvt — kills the
// largest VALU block), and Ct read as fp16 (half epilogue bytes).
__launch_bounds__(512, 6)
__global__ void k_main(const float* __restrict__ doc, const int* __restrict__ dmask,
                       const float* __restrict__ W1,
                       const float* __restrict__ w2, const float* __restrict__ b2,
                       const float* __restrict__ Bt, const _Float16* __restrict__ Ct16,
                       const _Float16* __restrict__ doc_h, float* __restrict__ out) {
  __shared__ __align__(16) _Float16 As[Hh * SP];  // fp16(W1a), e-window
  __shared__ __align__(16) _Float16 Bs[Hh * SP];  // fp16(doc), e-window
  __shared__ __align__(16) float sc[Ll];
  __shared__ __align__(16) float scw[Ll];

  int bid = blockIdx.x;
  int n = bid & 31, j = bid >> 5;   // XCD-locality swizzle
  int tid = threadIdx.x;
  const float* docn = doc + (size_t)n * Ll * Hh;
  size_t orow = ((size_t)n * Ll + j) * Hh;

  if (dmask[n * Ll + j] == 0) {     // fully-masked row -> exact zeros (~50% of blocks)
    if (tid < Hh) out[orow + tid] = 0.f;
    return;
  }

  int lane = tid & 63, wv = tid >> 6;   // 8 waves x 16 k-rows
  int l15 = lane & 15, quad = lane >> 4;
  int grow = tid >> 2, seg = (tid & 3) * 16;  // staging: row 0..127, 16-e segment

  const _Float16* dhn = doc_h + (size_t)n * Ll * Hh;

  floatx4 acc[8];
#pragma unroll
  for (int nt = 0; nt < 8; ++nt) acc[nt] = (floatx4){0.f, 0.f, 0.f, 0.f};

#pragma unroll
  for (int p = 0; p < 2; ++p) {
    if (p) __syncthreads();  // all waves done reading pass-0 window
    // stage this pass's 64-e window: doc from doc_h (no cvt), W1a with cvt
    {
      const f16x8* dsrc = (const f16x8*)(dhn + (size_t)grow * Hh + p * EP + seg);
      const float4* wsrc = (const float4*)(W1 + (size_t)grow * W1S + p * EP + seg);
      f16x8 d0 = dsrc[0], d1 = dsrc[1];
      float4 w0 = wsrc[0], w1 = wsrc[1], w2v = wsrc[2], w3 = wsrc[3];
      *(f16x8*)(Bs + grow * SP + seg) = d0;
      *(f16x8*)(Bs + grow * SP + seg + 8) = d1;
      *(f16x8*)(As + grow * SP + seg) = cvt8h(w0, w1);
      *(f16x8*)(As + grow * SP + seg + 8) = cvt8h(w2v, w3);
    }
    __syncthreads();
    // GEMM over this 64-e window
#pragma unroll
    for (int c = 0; c < 2; ++c) {
      int eo = c * 32 + quad * 8;
      f16x8 dr = *(const f16x8*)(Bs + (wv * 16 + l15) * SP + eo);
      f16x8 jr = *(const f16x8*)(Bs + j * SP + eo);   // uniform row -> broadcast
      f16x8 af = dr * jr;                              // 4x v_pk_mul_f16
#pragma unroll
      for (int nt = 0; nt < 8; ++nt) {
        f16x8 bfr = *(const f16x8*)(As + (nt * 16 + l15) * SP + eo);
        acc[nt] = __builtin_amdgcn_mfma_f32_16x16x32_f16(af, bfr, acc[nt], 0, 0, 0);
      }
    }
  }

  // epilogue: tanh(acc + Ct[k,g] + Bt[j,g]) . w2 -> sc[k]   (b1 folded into Bt)
  const float c2 = 2.885390081777927f;  // 2*log2(e)
  float bbc[8], w2r[8];
  const float* btrow = Bt + orow;
#pragma unroll
  for (int nt = 0; nt < 8; ++nt) {
    int g = nt * 16 + l15;
    bbc[nt] = btrow[g] * c2;
    w2r[nt] = w2[g];
  }
  const _Float16* ctn = Ct16 + (size_t)n * Ll * Hh;
#pragma unroll
  for (int r = 0; r < 4; ++r) {
    int k = wv * 16 + quad * 4 + r;
    const _Float16* ctp = ctn + (size_t)k * Hh + l15;
    float p = 0.f;
#pragma unroll
    for (int nt = 0; nt < 8; ++nt) {
      float s = acc[nt][r] + (float)ctp[nt * 16];
      float a2 = fmaf(s, c2, bbc[nt]);
      float e = exp2f(a2);
      float th = fmaf(-2.f, __builtin_amdgcn_rcpf(e + 1.f), 1.f);
      p = fmaf(th, w2r[nt], p);
    }
    p += __shfl_xor(p, 1);
    p += __shfl_xor(p, 2);
    p += __shfl_xor(p, 4);
    p += __shfl_xor(p, 8);
    if (l15 == 0) sc[k] = p;
  }
  __syncthreads();

  // redundant per-wave masked softmax (no extra barriers)
  {
    float b2v = b2[0];
    const float inv = 0.088388347648318447f;  // 1/sqrt(128)
    const int* dmn = dmask + n * Ll;
    int m0 = dmn[lane], m1 = dmn[lane + 64];
    float s0 = (sc[lane] + b2v) * inv;
    float s1 = (sc[lane + 64] + b2v) * inv;
    s0 = m0 ? s0 : -1e9f;
    s1 = m1 ? s1 : -1e9f;
    float mx = fmaxf(s0, s1);
#pragma unroll
    for (int off = 32; off; off >>= 1) mx = fmaxf(mx, __shfl_xor(mx, off));
    float ex0 = __expf(s0 - mx), ex1 = __expf(s1 - mx);
    float sm = ex0 + ex1;
#pragma unroll
    for (int off = 32; off; off >>= 1) sm += __shfl_xor(sm, off);
    float rden = 1.f / sm;
    scw[lane] = m0 ? ex0 * rden : 0.f;       // all 8 waves write identical values
    scw[lane + 64] = m1 ? ex1 * rden : 0.f;
  }
  __syncthreads();

  // out[j,h] = sum_k w[k] * doc[n,k,h] ; 4-way k-split across the 512 threads
  float* ored = (float*)As;  // As dead after GEMM (all waves past last barrier)
  int qk = tid >> 7, h = tid & 127;
  const float* dbase = docn + (size_t)qk * 32 * Hh + h;
  float o = 0.f;
#pragma unroll 8
  for (int kk = 0; kk < 32; ++kk)
    o = fmaf(scw[qk * 32 + kk], dbase[(size_t)kk * Hh], o);
  ored[qk * Hh + h] = o;
  __syncthreads();
  if (tid < Ll)
    out[orow + tid] = ored[tid] + ored[Hh + tid] + ored[2 * Hh + tid] + ored[3 * Hh + tid];
}

extern "C" void kernel_launch(void* const* d_in, const int* in_sizes, int n_in,
                              void* d_out, int out_size, void* d_ws, size_t ws_size,
                              hipStream_t stream) {
  const float* wei   = (const float*)d_in[0];
  const int*   wmask = (const int*)d_in[1];
  const float* doc   = (const float*)d_in[2];
  const int*   dmask = (const int*)d_in[3];
  const float* q     = (const float*)d_in[4];
  const float* W1    = (const float*)d_in[5];
  const float* b1    = (const float*)d_in[6];
  const float* w2    = (const float*)d_in[7];
  const float* b2    = (const float*)d_in[8];
  float* out = (float*)d_out;

  // ws layout (total exactly 4,194,304 B = previous usage):
  //   Bt fp32  [N*L*H]  2,097,152 B (b1 folded in)
  //   Ct fp16  [N*L*H]  1,048,576 B
  //   doc_h    [N*L*H]  1,048,576 B (raw doc, fp16)
  float* Bt = (float*)d_ws;
  _Float16* Ct16 = (_Float16*)(Bt + (size_t)Nn * Ll * Hh);
  _Float16* doc_h = Ct16 + (size_t)Nn * Ll * Hh;

  k_prep<<<Nn * 4, 256, 0, stream>>>(wei, wmask, doc, q, W1, b1, Bt, Ct16, doc_h);
  k_main<<<Nn * Ll, 512, 0, stream>>>(doc, dmask, W1, w2, b2, Bt, Ct16, doc_h, out);
}